// Round 1
// baseline (161.226 us; speedup 1.0000x reference)
//
#include <hip/hip_runtime.h>
#include <cstddef>

// Problem constants
constexpr int Bn  = 16;    // batch
constexpr int CIc = 32;    // in channels
constexpr int COc = 32;    // out channels
constexpr int Kc  = 16;    // kernel width
constexpr int IN  = 8192;  // input length
constexpr int OUTL = 8176; // output length = IN - K

// Tiling
constexpr int O_B  = 16;              // o-positions per block
constexpr int CCH  = 8;               // input channels staged per chunk
constexpr int NPOS = O_B + Kc - 1;    // 31 x-positions needed per block
constexpr int BST  = 20;              // padded batch stride in LDS (floats)

__global__ __launch_bounds__(256, 2)
void conv1d_cppn_kernel(const float* __restrict__ x, const float* __restrict__ w,
                        const float* __restrict__ bias, float* __restrict__ out) {
    // x staged transposed: xs[cc][pos][b] so b is contiguous -> float4 reads over b
    __shared__ float xs[CCH][NPOS][BST];   // 8*31*20*4 = 19,840 B

    const int tid = threadIdx.x;
    const int og = tid & 15;          // o within tile   (fast -> coalesced w)
    const int dg = (tid >> 4) & 7;    // d group (4 d's each)
    const int bg = tid >> 7;          // b group (8 b's each)
    const int o0 = blockIdx.x * O_B;
    const int o  = o0 + og;
    const int dbase = dg * 4;
    const int bbase = bg * 8;

    float acc[4][8];
#pragma unroll
    for (int i = 0; i < 4; ++i)
#pragma unroll
        for (int j = 0; j < 8; ++j) acc[i][j] = 0.f;

    for (int chunk = 0; chunk < CIc / CCH; ++chunk) {
        const int c0 = chunk * CCH;
        __syncthreads();
        // Stage x[b, c0..c0+CCH, o0 .. o0+NPOS) into LDS, transposed.
        // idx ordering: p fastest -> consecutive lanes read consecutive floats.
        for (int idx = tid; idx < CCH * Bn * NPOS; idx += 256) {
            const int p  = idx % NPOS;
            const int t  = idx / NPOS;
            const int b  = t & 15;
            const int cc = t >> 4;
            xs[cc][p][b] = x[((size_t)b * CIc + (c0 + cc)) * IN + o0 + p];
        }
        __syncthreads();

#pragma unroll 2
        for (int cc = 0; cc < CCH; ++cc) {
            const int c = c0 + cc;
            // Load w[d, c, o, 0..16) for 4 d's: 16 consecutive floats each.
            float wreg[4][16];
#pragma unroll
            for (int jd = 0; jd < 4; ++jd) {
                const float4* wp = reinterpret_cast<const float4*>(
                    w + (((size_t)(dbase + jd) * CIc + c) * OUTL + o) * Kc);
#pragma unroll
                for (int q = 0; q < 4; ++q) {
                    const float4 v = wp[q];
                    wreg[jd][q * 4 + 0] = v.x;
                    wreg[jd][q * 4 + 1] = v.y;
                    wreg[jd][q * 4 + 2] = v.z;
                    wreg[jd][q * 4 + 3] = v.w;
                }
            }
#pragma unroll
            for (int k = 0; k < Kc; ++k) {
                const float4 xa = *reinterpret_cast<const float4*>(&xs[cc][og + k][bbase]);
                const float4 xb = *reinterpret_cast<const float4*>(&xs[cc][og + k][bbase + 4]);
#pragma unroll
                for (int jd = 0; jd < 4; ++jd) {
                    const float wk = wreg[jd][k];
                    acc[jd][0] += wk * xa.x;
                    acc[jd][1] += wk * xa.y;
                    acc[jd][2] += wk * xa.z;
                    acc[jd][3] += wk * xa.w;
                    acc[jd][4] += wk * xb.x;
                    acc[jd][5] += wk * xb.y;
                    acc[jd][6] += wk * xb.z;
                    acc[jd][7] += wk * xb.w;
                }
            }
        }
    }

    // Epilogue: bias + relu, coalesced over o (consecutive lanes -> consecutive o)
#pragma unroll
    for (int jd = 0; jd < 4; ++jd) {
        const float bv = bias[dbase + jd];
#pragma unroll
        for (int jb = 0; jb < 8; ++jb) {
            float v = acc[jd][jb] + bv;
            out[((size_t)(bbase + jb) * COc + (dbase + jd)) * OUTL + o] = v > 0.f ? v : 0.f;
        }
    }
}

extern "C" void kernel_launch(void* const* d_in, const int* in_sizes, int n_in,
                              void* d_out, int out_size, void* d_ws, size_t ws_size,
                              hipStream_t stream) {
    const float* x    = (const float*)d_in[0];
    const float* w    = (const float*)d_in[1];
    const float* bias = (const float*)d_in[2];
    float* out        = (float*)d_out;

    dim3 grid(OUTL / O_B);  // 8176/16 = 511, exact
    dim3 block(256);
    hipLaunchKernelGGL(conv1d_cppn_kernel, grid, block, 0, stream, x, w, bias, out);
}

// Round 2
// 121.907 us; speedup vs baseline: 1.3225x; 1.3225x over previous
//
#include <hip/hip_runtime.h>
#include <cstddef>

// Problem constants
constexpr int Bn  = 16;    // batch
constexpr int CIc = 32;    // in channels
constexpr int COc = 32;    // out channels
constexpr int Kc  = 16;    // kernel width
constexpr int IN  = 8192;  // input length
constexpr int OUTL = 8176; // output length = IN - K

// Tiling
constexpr int O_B  = 16;              // o-positions per block
constexpr int CCH  = 8;               // input channels staged per chunk
constexpr int NPOS = O_B + Kc - 1;    // 31 x-positions needed per block
constexpr int BST  = 20;              // padded batch stride in LDS (floats)

__global__ __launch_bounds__(256, 2)
void conv1d_cppn_kernel(const float* __restrict__ x, const float* __restrict__ w,
                        const float* __restrict__ bias, float* __restrict__ out) {
    // x staged transposed: xs[cc][pos][b] so b is contiguous -> float4 reads over b
    __shared__ float xs[CCH][NPOS][BST];   // 8*31*20*4 = 19,840 B

    const int tid = threadIdx.x;
    const int og = tid & 15;          // o within tile (fast -> coalesced w loads)
    const int dg = tid >> 4;          // d group: 2 d's per thread, 16 groups
    const int o0 = blockIdx.x * O_B;
    const int o  = o0 + og;
    const int dbase = dg * 2;

    // Each thread owns 2 output channels x ALL 16 batches for one o.
    // => every w element is loaded by exactly ONE thread grid-wide.
    float acc[2][16];
#pragma unroll
    for (int i = 0; i < 2; ++i)
#pragma unroll
        for (int j = 0; j < 16; ++j) acc[i][j] = 0.f;

    for (int chunk = 0; chunk < CIc / CCH; ++chunk) {
        const int c0 = chunk * CCH;
        __syncthreads();
        // Stage x[b, c0..c0+CCH, o0 .. o0+NPOS) into LDS, transposed.
        // p fastest -> consecutive lanes read consecutive floats (coalesced).
        for (int idx = tid; idx < CCH * Bn * NPOS; idx += 256) {
            const int p  = idx % NPOS;
            const int t  = idx / NPOS;
            const int b  = t & 15;
            const int cc = t >> 4;
            xs[cc][p][b] = x[((size_t)b * CIc + (c0 + cc)) * IN + o0 + p];
        }
        __syncthreads();

#pragma unroll 2
        for (int cc = 0; cc < CCH; ++cc) {
            const int c = c0 + cc;
            // Load w[d, c, o, 0..16) for this thread's 2 d's: 64B contiguous each.
            float wreg[2][16];
#pragma unroll
            for (int jd = 0; jd < 2; ++jd) {
                const float4* wp = reinterpret_cast<const float4*>(
                    w + (((size_t)(dbase + jd) * CIc + c) * OUTL + o) * Kc);
#pragma unroll
                for (int q = 0; q < 4; ++q) {
                    const float4 v = wp[q];
                    wreg[jd][q * 4 + 0] = v.x;
                    wreg[jd][q * 4 + 1] = v.y;
                    wreg[jd][q * 4 + 2] = v.z;
                    wreg[jd][q * 4 + 3] = v.w;
                }
            }
#pragma unroll
            for (int k = 0; k < Kc; ++k) {
                float xv[16];
                *reinterpret_cast<float4*>(&xv[0])  = *reinterpret_cast<const float4*>(&xs[cc][og + k][0]);
                *reinterpret_cast<float4*>(&xv[4])  = *reinterpret_cast<const float4*>(&xs[cc][og + k][4]);
                *reinterpret_cast<float4*>(&xv[8])  = *reinterpret_cast<const float4*>(&xs[cc][og + k][8]);
                *reinterpret_cast<float4*>(&xv[12]) = *reinterpret_cast<const float4*>(&xs[cc][og + k][12]);
#pragma unroll
                for (int jd = 0; jd < 2; ++jd) {
                    const float wk = wreg[jd][k];
#pragma unroll
                    for (int jb = 0; jb < 16; ++jb) {
                        acc[jd][jb] += wk * xv[jb];
                    }
                }
            }
        }
    }

    // Epilogue: bias + relu, coalesced over o (consecutive lanes -> consecutive o)
#pragma unroll
    for (int jd = 0; jd < 2; ++jd) {
        const float bv = bias[dbase + jd];
#pragma unroll
        for (int jb = 0; jb < 16; ++jb) {
            float v = acc[jd][jb] + bv;
            out[((size_t)jb * COc + (dbase + jd)) * OUTL + o] = v > 0.f ? v : 0.f;
        }
    }
}

extern "C" void kernel_launch(void* const* d_in, const int* in_sizes, int n_in,
                              void* d_out, int out_size, void* d_ws, size_t ws_size,
                              hipStream_t stream) {
    const float* x    = (const float*)d_in[0];
    const float* w    = (const float*)d_in[1];
    const float* bias = (const float*)d_in[2];
    float* out        = (float*)d_out;

    dim3 grid(OUTL / O_B);  // 8176/16 = 511, exact
    dim3 block(256);
    hipLaunchKernelGGL(conv1d_cppn_kernel, grid, block, 0, stream, x, w, bias, out);
}